// Round 1
// baseline (2671.302 us; speedup 1.0000x reference)
//
#include <hip/hip_runtime.h>
#include <cstdint>
#include <cstddef>

#define HIDDEN   2048
#define NH       16
#define NKV      4
#define HD       128
#define SEQ      2048
#define BATCH    2
#define NTOK     (BATCH*SEQ)      // 4096
#define QKV_LD   3072             // Q(2048) | K(512) | V(512)
#define KOFF     2048
#define VOFF     2560
#define SM_SCALE 0.08838834764831845f   // 1/sqrt(128)

// ---------------- fp32 GEMM, 128x128 tile, BK=8, 256 threads, 8x8/thread --------
__device__ __forceinline__ void gemm128_body(
    const float* __restrict__ Arow, int lda,     // A + bm*lda
    const float* __restrict__ Wcol, int ldw,     // W + wn  (col offset applied)
    float* __restrict__ Cptr, int ldc, int K,    // C + bm*ldc + bn
    float (*As)[128], float (*Bs)[128])
{
  const int t  = threadIdx.x;
  const int tx = t & 15, ty = t >> 4;
  const int am = t >> 1, ak = (t & 1) * 4;     // A loader: row am, k-quad ak
  const int bk = t >> 5, bn = (t & 31) * 4;    // B loader: k row bk, col quad bn

  float acc[8][8];
  #pragma unroll
  for (int i = 0; i < 8; ++i)
    #pragma unroll
    for (int j = 0; j < 8; ++j) acc[i][j] = 0.f;

  for (int k0 = 0; k0 < K; k0 += 8) {
    const float4 a4 = *(const float4*)(Arow + (size_t)am * lda + k0 + ak);
    const float4 b4 = *(const float4*)(Wcol + (size_t)(k0 + bk) * ldw + bn);
    __syncthreads();                      // previous tile's compute done
    As[ak+0][am] = a4.x; As[ak+1][am] = a4.y;
    As[ak+2][am] = a4.z; As[ak+3][am] = a4.w;
    *(float4*)&Bs[bk][bn] = b4;
    __syncthreads();
    #pragma unroll
    for (int kk = 0; kk < 8; ++kk) {
      float a[8], b[8];
      *(float4*)&a[0] = *(const float4*)&As[kk][ty*8];
      *(float4*)&a[4] = *(const float4*)&As[kk][ty*8+4];
      *(float4*)&b[0] = *(const float4*)&Bs[kk][tx*8];
      *(float4*)&b[4] = *(const float4*)&Bs[kk][tx*8+4];
      #pragma unroll
      for (int i = 0; i < 8; ++i)
        #pragma unroll
        for (int j = 0; j < 8; ++j)
          acc[i][j] = fmaf(a[i], b[j], acc[i][j]);
    }
  }

  #pragma unroll
  for (int i = 0; i < 8; ++i) {
    float* cr = Cptr + (size_t)(ty*8 + i) * ldc + tx*8;
    *(float4*)cr       = make_float4(acc[i][0], acc[i][1], acc[i][2], acc[i][3]);
    *(float4*)(cr + 4) = make_float4(acc[i][4], acc[i][5], acc[i][6], acc[i][7]);
  }
}

// C[4096][3072] = H @ [Wq | Wk | Wv]
__global__ __launch_bounds__(256) void qkv_gemm(
    const float* __restrict__ A, const float* __restrict__ Wq,
    const float* __restrict__ Wk, const float* __restrict__ Wv,
    float* __restrict__ C)
{
  __shared__ float As[8][128];
  __shared__ float Bs[8][128];
  const int bm = blockIdx.y * 128;
  const int bn = blockIdx.x * 128;
  const float* W; int ldw, wn;
  if (bn < HIDDEN)            { W = Wq; ldw = HIDDEN; wn = bn; }
  else if (bn < VOFF)         { W = Wk; ldw = NKV*HD; wn = bn - KOFF; }
  else                        { W = Wv; ldw = NKV*HD; wn = bn - VOFF; }
  gemm128_body(A + (size_t)bm * HIDDEN, HIDDEN, W + wn, ldw,
               C + (size_t)bm * QKV_LD + bn, QKV_LD, HIDDEN, As, Bs);
}

// out[4096][2048] = Oattn @ Wo
__global__ __launch_bounds__(256) void out_gemm(
    const float* __restrict__ A, const float* __restrict__ Wo, float* __restrict__ C)
{
  __shared__ float As[8][128];
  __shared__ float Bs[8][128];
  const int bm = blockIdx.y * 128;
  const int bn = blockIdx.x * 128;
  gemm128_body(A + (size_t)bm * HIDDEN, HIDDEN, Wo + bn, HIDDEN,
               C + (size_t)bm * HIDDEN + bn, HIDDEN, HIDDEN, As, Bs);
}

// In-place RoPE on Q (16 heads) and K (4 heads) inside the QKV buffer.
// q'[i]    = q[i]*cos - q[i+64]*sin ; q'[i+64] = q[i+64]*cos + q[i]*sin
__global__ __launch_bounds__(256) void rope_kernel(float* __restrict__ QKV)
{
  const int total = NTOK * (NH + NKV) * (HD/2);
  int idx = blockIdx.x * 256 + threadIdx.x;
  if (idx >= total) return;
  const int i   = idx & 63;
  int tmp = idx >> 6;
  const int hs  = tmp % (NH + NKV);
  const int tkn = tmp / (NH + NKV);
  const int s   = tkn & (SEQ - 1);
  // inv_freq = 10000^(-i/64) = exp(-i * ln(10000)/64)
  const float invf = expf(-(float)i * 0.14391156831212787f);
  float sn, cs;
  sincosf((float)s * invf, &sn, &cs);
  const size_t base = (size_t)tkn * QKV_LD + (hs < NH ? hs * HD : KOFF + (hs - NH) * HD);
  const float x0 = QKV[base + i];
  const float x1 = QKV[base + i + 64];
  QKV[base + i]      = x0 * cs - x1 * sn;
  QKV[base + i + 64] = x1 * cs + x0 * sn;
}

// Causal GQA flash attention, fp32. Block = 64 q-rows of one (b,h).
// Thread (r = t/4, c = t%4) owns q-row r, dims [c*32, c*32+32).
// K/V LDS layout is dim-interleaved: float4 line (row j, i, c) at j*128 + i*16 + c*4,
// holding global dims d = c*32 + i*4 .. +3  -> inner-loop reads hit 4 distinct banks
// with 16-lane broadcast (conflict-free) instead of 4-way same-bank.
__global__ __launch_bounds__(256) void attn_kernel(
    const float* __restrict__ QKV, float* __restrict__ O)
{
  __shared__ float Kl[64*128];
  __shared__ float Vl[64*128];
  const int qb = blockIdx.x, bh = blockIdx.y;
  const int b = bh >> 4, h = bh & 15, hk = h >> 2;
  const int t = threadIdx.x;
  const int r = t >> 2, c = t & 3;
  const int qs = qb * 64 + r;

  float q[32];
  {
    const float4* qp = (const float4*)(QKV + (size_t)(b*SEQ + qs) * QKV_LD + h*HD + c*32);
    #pragma unroll
    for (int i = 0; i < 8; ++i) {
      const float4 v = qp[i];
      q[4*i] = v.x; q[4*i+1] = v.y; q[4*i+2] = v.z; q[4*i+3] = v.w;
    }
  }
  float acc[32];
  #pragma unroll
  for (int i = 0; i < 32; ++i) acc[i] = 0.f;
  float m = -1e30f, l = 0.f;

  for (int kt = 0; kt <= qb; ++kt) {
    {
      const float* kg = QKV + (size_t)(b*SEQ + kt*64 + r) * QKV_LD + KOFF + hk*HD + c*32;
      const float4* kgp = (const float4*)kg;
      const float4* vgp = (const float4*)(kg + (VOFF - KOFF));
      #pragma unroll
      for (int i = 0; i < 8; ++i) {
        *(float4*)&Kl[r*128 + i*16 + c*4] = kgp[i];
        *(float4*)&Vl[r*128 + i*16 + c*4] = vgp[i];
      }
    }
    __syncthreads();
    const bool diag = (kt == qb);
    for (int j = 0; j < 64; ++j) {
      float s = 0.f;
      #pragma unroll
      for (int i = 0; i < 8; ++i) {
        const float4 kv = *(const float4*)&Kl[j*128 + i*16 + c*4];
        s = fmaf(q[4*i],   kv.x, s); s = fmaf(q[4*i+1], kv.y, s);
        s = fmaf(q[4*i+2], kv.z, s); s = fmaf(q[4*i+3], kv.w, s);
      }
      s += __shfl_xor(s, 1);     // reduce across the 4 dim-groups of this row
      s += __shfl_xor(s, 2);
      s *= SM_SCALE;
      if (diag && j > r) s = -1e30f;   // causal mask (only diagonal tile)
      if (s > m) {                     // lazy rescale; key 0 always unmasked -> m finite
        const float corr = __expf(m - s);
        m = s; l *= corr;
        #pragma unroll
        for (int i = 0; i < 32; ++i) acc[i] *= corr;
      }
      const float p = __expf(s - m);
      l += p;
      #pragma unroll
      for (int i = 0; i < 8; ++i) {
        const float4 vv = *(const float4*)&Vl[j*128 + i*16 + c*4];
        acc[4*i]   = fmaf(p, vv.x, acc[4*i]);
        acc[4*i+1] = fmaf(p, vv.y, acc[4*i+1]);
        acc[4*i+2] = fmaf(p, vv.z, acc[4*i+2]);
        acc[4*i+3] = fmaf(p, vv.w, acc[4*i+3]);
      }
    }
    __syncthreads();
  }

  const float inv_l = 1.f / l;
  float4* op = (float4*)(O + (size_t)(b*SEQ + qs) * HIDDEN + h*HD + c*32);
  #pragma unroll
  for (int i = 0; i < 8; ++i)
    op[i] = make_float4(acc[4*i]*inv_l, acc[4*i+1]*inv_l,
                        acc[4*i+2]*inv_l, acc[4*i+3]*inv_l);
}

extern "C" void kernel_launch(void* const* d_in, const int* in_sizes, int n_in,
                              void* d_out, int out_size, void* d_ws, size_t ws_size,
                              hipStream_t stream)
{
  (void)in_sizes; (void)n_in; (void)out_size; (void)ws_size;
  const float* H  = (const float*)d_in[0];
  const float* Wq = (const float*)d_in[1];
  const float* Wk = (const float*)d_in[2];
  const float* Wv = (const float*)d_in[3];
  const float* Wo = (const float*)d_in[4];
  float* out = (float*)d_out;

  float* QKV = (float*)d_ws;                       // [4096][3072]
  float* Oat = QKV + (size_t)NTOK * QKV_LD;        // [4096][2048]

  qkv_gemm<<<dim3(QKV_LD/128, NTOK/128), 256, 0, stream>>>(H, Wq, Wk, Wv, QKV);

  const int rope_total = NTOK * (NH + NKV) * (HD/2);
  rope_kernel<<<(rope_total + 255)/256, 256, 0, stream>>>(QKV);

  attn_kernel<<<dim3(SEQ/64, BATCH*NH), 256, 0, stream>>>(QKV, Oat);

  out_gemm<<<dim3(HIDDEN/128, NTOK/128), 256, 0, stream>>>(Oat, Wo, out);
}

// Round 3
// 1295.716 us; speedup vs baseline: 2.0616x; 2.0616x over previous
//
#include <hip/hip_runtime.h>
#include <hip/hip_bf16.h>
#include <cstdint>
#include <cstddef>

#define HIDDEN   2048
#define NH       16
#define NKV      4
#define HD       128
#define SEQ      2048
#define BATCH    2
#define NTOK     (BATCH*SEQ)      // 4096
#define QKV_LD   3072             // Q(2048) | K(512) | V(512)
#define KOFF     2048
#define VOFF     2560
#define SM_SCALE 0.08838834764831845f   // 1/sqrt(128)

typedef __attribute__((ext_vector_type(8)))  short bf16x8;
typedef __attribute__((ext_vector_type(16))) float f32x16;

__device__ __forceinline__ unsigned short f2bf(float f) {
  return __builtin_bit_cast(unsigned short, __float2bfloat16(f));
}
__device__ __forceinline__ unsigned pack2(float a, float b) {
  return (unsigned)f2bf(a) | ((unsigned)f2bf(b) << 16);
}

// ---------------- fp32 GEMM, 128x128 tile, BK=8, 256 threads, 8x8/thread --------
__device__ __forceinline__ void gemm128_body(
    const float* __restrict__ Arow, int lda,
    const float* __restrict__ Wcol, int ldw,
    float* __restrict__ Cptr, int ldc, int K,
    float (*As)[128], float (*Bs)[128])
{
  const int t  = threadIdx.x;
  const int tx = t & 15, ty = t >> 4;
  const int am = t >> 1, ak = (t & 1) * 4;
  const int bk = t >> 5, bn = (t & 31) * 4;

  float acc[8][8];
  #pragma unroll
  for (int i = 0; i < 8; ++i)
    #pragma unroll
    for (int j = 0; j < 8; ++j) acc[i][j] = 0.f;

  for (int k0 = 0; k0 < K; k0 += 8) {
    const float4 a4 = *(const float4*)(Arow + (size_t)am * lda + k0 + ak);
    const float4 b4 = *(const float4*)(Wcol + (size_t)(k0 + bk) * ldw + bn);
    __syncthreads();
    As[ak+0][am] = a4.x; As[ak+1][am] = a4.y;
    As[ak+2][am] = a4.z; As[ak+3][am] = a4.w;
    *(float4*)&Bs[bk][bn] = b4;
    __syncthreads();
    #pragma unroll
    for (int kk = 0; kk < 8; ++kk) {
      float a[8], b[8];
      *(float4*)&a[0] = *(const float4*)&As[kk][ty*8];
      *(float4*)&a[4] = *(const float4*)&As[kk][ty*8+4];
      *(float4*)&b[0] = *(const float4*)&Bs[kk][tx*8];
      *(float4*)&b[4] = *(const float4*)&Bs[kk][tx*8+4];
      #pragma unroll
      for (int i = 0; i < 8; ++i)
        #pragma unroll
        for (int j = 0; j < 8; ++j)
          acc[i][j] = fmaf(a[i], b[j], acc[i][j]);
    }
  }

  #pragma unroll
  for (int i = 0; i < 8; ++i) {
    float* cr = Cptr + (size_t)(ty*8 + i) * ldc + tx*8;
    *(float4*)cr       = make_float4(acc[i][0], acc[i][1], acc[i][2], acc[i][3]);
    *(float4*)(cr + 4) = make_float4(acc[i][4], acc[i][5], acc[i][6], acc[i][7]);
  }
}

__global__ __launch_bounds__(256) void qkv_gemm(
    const float* __restrict__ A, const float* __restrict__ Wq,
    const float* __restrict__ Wk, const float* __restrict__ Wv,
    float* __restrict__ C)
{
  __shared__ float As[8][128];
  __shared__ float Bs[8][128];
  const int bm = blockIdx.y * 128;
  const int bn = blockIdx.x * 128;
  const float* W; int ldw, wn;
  if (bn < HIDDEN)            { W = Wq; ldw = HIDDEN; wn = bn; }
  else if (bn < VOFF)         { W = Wk; ldw = NKV*HD; wn = bn - KOFF; }
  else                        { W = Wv; ldw = NKV*HD; wn = bn - VOFF; }
  gemm128_body(A + (size_t)bm * HIDDEN, HIDDEN, W + wn, ldw,
               C + (size_t)bm * QKV_LD + bn, QKV_LD, HIDDEN, As, Bs);
}

__global__ __launch_bounds__(256) void out_gemm(
    const float* __restrict__ A, const float* __restrict__ Wo, float* __restrict__ C)
{
  __shared__ float As[8][128];
  __shared__ float Bs[8][128];
  const int bm = blockIdx.y * 128;
  const int bn = blockIdx.x * 128;
  gemm128_body(A + (size_t)bm * HIDDEN, HIDDEN, Wo + bn, HIDDEN,
               C + (size_t)bm * HIDDEN + bn, HIDDEN, HIDDEN, As, Bs);
}

// In-place RoPE on Q and K inside the QKV buffer.
__global__ __launch_bounds__(256) void rope_kernel(float* __restrict__ QKV)
{
  const int total = NTOK * (NH + NKV) * (HD/2);
  int idx = blockIdx.x * 256 + threadIdx.x;
  if (idx >= total) return;
  const int i   = idx & 63;
  int tmp = idx >> 6;
  const int hs  = tmp % (NH + NKV);
  const int tkn = tmp / (NH + NKV);
  const int s   = tkn & (SEQ - 1);
  const float invf = expf(-(float)i * 0.14391156831212787f);
  float sn, cs;
  sincosf((float)s * invf, &sn, &cs);
  const size_t base = (size_t)tkn * QKV_LD + (hs < NH ? hs * HD : KOFF + (hs - NH) * HD);
  const float x0 = QKV[base + i];
  const float x1 = QKV[base + i + 64];
  QKV[base + i]      = x0 * cs - x1 * sn;
  QKV[base + i + 64] = x1 * cs + x0 * sn;
}

// ---------------- MFMA flash attention (bf16 inputs, fp32 accum) ----------------
// Block: 4 waves x 32 q-rows = 128 q-rows of one (b,h). KV tile = 64 keys.
// Swapped QK^T: S^T = K . Q^T  -> D col(lane&31) = q-row, row(reg) = key  => softmax lane-local.
// PV as O^T = V^T . P^T        -> D col(lane&31) = q-row again            => rescale lane-local.
// LDS: Kl[key][dim] bf16 swizzled ^((row&15)<<4), Vt[dim][key] swizzled ^((row&7)<<4),
//      Pl per-wave [qrow][key] swizzled ^((row&7)<<4). All ds_read_b128 are 8 words/bank = conflict-free.
__global__ __launch_bounds__(256) void attn_mfma(
    const float* __restrict__ QKV, float* __restrict__ O)
{
  __shared__ unsigned short Kl[64*128];
  __shared__ unsigned short Vt[128*64];
  __shared__ unsigned short Pl[4][32*64];

  const int qb = blockIdx.x, bh = blockIdx.y;
  const int b = bh >> 4, h = bh & 15, hk = h >> 2;
  const int t = threadIdx.x, w = t >> 6, lane = t & 63;
  const int c = lane & 31, hi = lane >> 5;
  const int qw0 = qb*128 + w*32;        // wave's first q-row
  const int qg  = qw0 + c;              // this lane's q-row

  // Q B-fragments (scale folded in): qf[kc] holds Q[qg][kc*16 + hi*8 + i], i=0..7
  bf16x8 qf[8];
  {
    const float* qrow = QKV + (size_t)(b*SEQ + qg) * QKV_LD + h*HD;
    #pragma unroll
    for (int kc = 0; kc < 8; ++kc) {
      const float4 f0 = *(const float4*)(qrow + kc*16 + hi*8);
      const float4 f1 = *(const float4*)(qrow + kc*16 + hi*8 + 4);
      bf16x8 v;
      v[0] = (short)f2bf(f0.x*SM_SCALE); v[1] = (short)f2bf(f0.y*SM_SCALE);
      v[2] = (short)f2bf(f0.z*SM_SCALE); v[3] = (short)f2bf(f0.w*SM_SCALE);
      v[4] = (short)f2bf(f1.x*SM_SCALE); v[5] = (short)f2bf(f1.y*SM_SCALE);
      v[6] = (short)f2bf(f1.z*SM_SCALE); v[7] = (short)f2bf(f1.w*SM_SCALE);
      qf[kc] = v;
    }
  }

  f32x16 ot[4];
  #pragma unroll
  for (int nc = 0; nc < 4; ++nc)
    #pragma unroll
    for (int r = 0; r < 16; ++r) ot[nc][r] = 0.f;
  float m = -1e30f, l = 0.f;

  char* klb = (char*)Kl;
  char* vtb = (char*)Vt;
  char* plb = (char*)Pl[w];
  const int ktmax = 2*qb + 1;

  for (int kt = 0; kt <= ktmax; ++kt) {
    __syncthreads();   // previous tile's LDS reads done before overwrite
    // ---- stage K tile: Kl[key][dim], bf16, swizzled
    {
      const int row = t >> 2, cq = t & 3;
      const float* kg = QKV + (size_t)(b*SEQ + kt*64 + row) * QKV_LD + KOFF + hk*HD + cq*32;
      const int sw = (row & 15) << 4;
      #pragma unroll
      for (int u = 0; u < 8; ++u) {
        const float4 f = ((const float4*)kg)[u];
        uint2 pv;
        pv.x = pack2(f.x, f.y); pv.y = pack2(f.z, f.w);
        *(uint2*)(klb + row*256 + ((cq*64 + u*8) ^ sw)) = pv;
      }
    }
    // ---- stage V^T tile: Vt[dim][key], bf16, swizzled (pack 2 keys per b32)
    #pragma unroll
    for (int j = 0; j < 2; ++j) {
      const int tid = t + 256*j;
      const int kp = tid & 31, dc = tid >> 5;   // key-pair, dim-chunk(8)
      const float* vg = QKV + (size_t)(b*SEQ + kt*64 + 2*kp) * QKV_LD + VOFF + hk*HD + dc*8;
      const float4 a0 = *(const float4*)vg,            a1 = *(const float4*)(vg + 4);
      const float4 b0 = *(const float4*)(vg + QKV_LD), b1 = *(const float4*)(vg + QKV_LD + 4);
      const float x0[8] = {a0.x,a0.y,a0.z,a0.w,a1.x,a1.y,a1.z,a1.w};
      const float x1[8] = {b0.x,b0.y,b0.z,b0.w,b1.x,b1.y,b1.z,b1.w};
      #pragma unroll
      for (int jd = 0; jd < 8; ++jd) {
        const int d = dc*8 + jd;
        *(unsigned*)(vtb + d*128 + ((kp*4) ^ ((d & 7) << 4))) = pack2(x0[jd], x1[jd]);
      }
    }
    __syncthreads();

    if (kt*64 > qw0 + 31) continue;   // fully-masked tile for this wave (barriers stay aligned)

    // ---- QK^T (swapped): s[kn] = K-group . Q^T, D: col=qrow, row=key
    f32x16 s[2];
    #pragma unroll
    for (int kn = 0; kn < 2; ++kn)
      #pragma unroll
      for (int r = 0; r < 16; ++r) s[kn][r] = 0.f;
    #pragma unroll
    for (int kn = 0; kn < 2; ++kn) {
      const int row = kn*32 + c;
      const int sw = (row & 15) << 4;
      #pragma unroll
      for (int kc = 0; kc < 8; ++kc) {
        const bf16x8 ka = *(const bf16x8*)(klb + row*256 + ((kc*32 + hi*16) ^ sw));
        s[kn] = __builtin_amdgcn_mfma_f32_32x32x16_bf16(ka, qf[kc], s[kn], 0, 0, 0);
      }
    }
    // ---- causal mask. Needed iff tile extends past the wave's FIRST q-row
    // (kt*64+63 > qw0), NOT past the last q-row — odd waves (qw0 = 64a+32) have a
    // diagonal tile kt*64 = qw0-32 that must be masked. (R2 bug: compared vs qw0+31.)
    if (kt*64 + 63 > qw0) {
      #pragma unroll
      for (int kn = 0; kn < 2; ++kn)
        #pragma unroll
        for (int r = 0; r < 16; ++r) {
          const int kg_ = kt*64 + kn*32 + (r & 3) + 8*(r >> 2) + 4*hi;
          if (kg_ > qg) s[kn][r] = -1e30f;
        }
    }
    // ---- online softmax (q-row = lane&31; keys split across hi halves)
    float mx[16];
    #pragma unroll
    for (int r = 0; r < 16; ++r) mx[r] = fmaxf(s[0][r], s[1][r]);
    #pragma unroll
    for (int st = 8; st > 0; st >>= 1)
      #pragma unroll
      for (int r = 0; r < 8; ++r)
        if (r < st) mx[r] = fmaxf(mx[r], mx[r + st]);
    float pm = fmaxf(mx[0], __shfl_xor(mx[0], 32));
    const float mnew = fmaxf(m, pm);
    const float corr = __expf(m - mnew);
    m = mnew;
    l *= corr;
    #pragma unroll
    for (int nc = 0; nc < 4; ++nc) ot[nc] *= corr;
    float ls = 0.f;
    #pragma unroll
    for (int kn = 0; kn < 2; ++kn)
      #pragma unroll
      for (int r = 0; r < 16; ++r) {
        const float p = __expf(s[kn][r] - m);
        ls += p;
        s[kn][r] = p;
      }
    l += ls;
    // ---- P^T -> Pl[qrow][key] (bf16, pairs of adjacent keys)
    {
      const int swp = (c & 7) << 4;
      #pragma unroll
      for (int kn = 0; kn < 2; ++kn)
        #pragma unroll
        for (int r = 0; r < 16; r += 2) {
          const int key = kn*32 + (r & 3) + 8*(r >> 2) + 4*hi;
          *(unsigned*)(plb + c*128 + ((key*2) ^ swp)) = pack2(s[kn][r], s[kn][r+1]);
        }
    }
    asm volatile("s_waitcnt lgkmcnt(0)" ::: "memory");   // own-wave Pl write->read
    // ---- PV: O^T += V^T-chunk . P^T-chunk, D: col=qrow, row=dim
    #pragma unroll
    for (int kc = 0; kc < 4; ++kc) {
      const bf16x8 pb = *(const bf16x8*)(plb + c*128 + ((kc*32 + hi*16) ^ ((c & 7) << 4)));
      #pragma unroll
      for (int nc = 0; nc < 4; ++nc) {
        const int dim = nc*32 + c;
        const bf16x8 va = *(const bf16x8*)(vtb + dim*128 + ((kc*32 + hi*16) ^ ((dim & 7) << 4)));
        ot[nc] = __builtin_amdgcn_mfma_f32_32x32x16_bf16(va, pb, ot[nc], 0, 0, 0);
      }
    }
  }

  // ---- epilogue: combine l across hi halves, normalize, write O[qrow][dim]
  const float lt = l + __shfl_xor(l, 32);
  const float inv = 1.f / lt;
  float* orow = O + (size_t)(b*SEQ + qg) * HIDDEN + h*HD;
  #pragma unroll
  for (int nc = 0; nc < 4; ++nc)
    #pragma unroll
    for (int r = 0; r < 16; r += 2) {
      const int dim = nc*32 + (r & 3) + 8*(r >> 2) + 4*hi;
      *(float2*)(orow + dim) = make_float2(ot[nc][r]*inv, ot[nc][r+1]*inv);
    }
}

extern "C" void kernel_launch(void* const* d_in, const int* in_sizes, int n_in,
                              void* d_out, int out_size, void* d_ws, size_t ws_size,
                              hipStream_t stream)
{
  (void)in_sizes; (void)n_in; (void)out_size; (void)ws_size;
  const float* H  = (const float*)d_in[0];
  const float* Wq = (const float*)d_in[1];
  const float* Wk = (const float*)d_in[2];
  const float* Wv = (const float*)d_in[3];
  const float* Wo = (const float*)d_in[4];
  float* out = (float*)d_out;

  float* QKV = (float*)d_ws;                       // [4096][3072]
  float* Oat = QKV + (size_t)NTOK * QKV_LD;        // [4096][2048]

  qkv_gemm<<<dim3(QKV_LD/128, NTOK/128), 256, 0, stream>>>(H, Wq, Wk, Wv, QKV);

  const int rope_total = NTOK * (NH + NKV) * (HD/2);
  rope_kernel<<<(rope_total + 255)/256, 256, 0, stream>>>(QKV);

  attn_mfma<<<dim3(SEQ/128, BATCH*NH), 256, 0, stream>>>(QKV, Oat);

  out_gemm<<<dim3(HIDDEN/128, NTOK/128), 256, 0, stream>>>(Oat, Wo, out);
}

// Round 4
// 410.395 us; speedup vs baseline: 6.5091x; 3.1572x over previous
//
#include <hip/hip_runtime.h>
#include <hip/hip_bf16.h>
#include <cstdint>
#include <cstddef>

#define HIDDEN   2048
#define NH       16
#define NKV      4
#define HD       128
#define SEQ      2048
#define BATCH    2
#define NTOK     (BATCH*SEQ)      // 4096
#define QKV_LD   3072             // Q(2048) | K(512) | V(512)
#define KOFF     2048
#define VOFF     2560
#define SM_SCALE 0.08838834764831845f   // 1/sqrt(128)

typedef __attribute__((ext_vector_type(8)))  short bf16x8;
typedef __attribute__((ext_vector_type(4)))  float f32x4v;
typedef __attribute__((ext_vector_type(16))) float f32x16;
typedef unsigned short ushort_t;

__device__ __forceinline__ unsigned short f2bf(float f) {
  return __builtin_bit_cast(unsigned short, __float2bfloat16(f));
}
__device__ __forceinline__ unsigned pack2(float a, float b) {
  return (unsigned)f2bf(a) | ((unsigned)f2bf(b) << 16);
}

// async global->LDS, 16B per lane. LDS dest must be lane-linear (wave base + lane*16);
// swizzled layouts are realized by pre-swizzling the GLOBAL source address (m173 pattern).
__device__ __forceinline__ void gload16(const void* g, void* l) {
  __builtin_amdgcn_global_load_lds(
      (const __attribute__((address_space(1))) unsigned int*)g,
      (__attribute__((address_space(3))) unsigned int*)l, 16, 0, 0);
}

// ---------------- conversion kernels ----------------
// fp32 -> bf16, 8 elems/thread
__global__ __launch_bounds__(256) void conv_f2b(
    const float* __restrict__ in, ushort_t* __restrict__ out, int n8)
{
  const int i = blockIdx.x*256 + threadIdx.x;
  if (i >= n8) return;
  const float4 a = ((const float4*)in)[2*i];
  const float4 b = ((const float4*)in)[2*i + 1];
  uint4 r;
  r.x = pack2(a.x, a.y); r.y = pack2(a.z, a.w);
  r.z = pack2(b.x, b.y); r.w = pack2(b.z, b.w);
  ((uint4*)out)[i] = r;
}

// W[K][N] fp32 -> Wt[N][K] bf16 (32x32 LDS tile, +1 pad)
__global__ __launch_bounds__(256) void transpose_f2b(
    const float* __restrict__ W, ushort_t* __restrict__ Wt, int K, int N)
{
  __shared__ float tile[32][33];
  const int n0 = blockIdx.x*32, k0 = blockIdx.y*32;
  const int tx = threadIdx.x, ty = threadIdx.y;
  #pragma unroll
  for (int i = 0; i < 4; ++i)
    tile[ty*4 + i][tx] = W[(size_t)(k0 + ty*4 + i)*N + n0 + tx];
  __syncthreads();
  #pragma unroll
  for (int i = 0; i < 4; ++i) {
    const int nl = ty*4 + i;
    Wt[(size_t)(n0 + nl)*K + k0 + tx] = f2bf(tile[tx][nl]);
  }
}

// ---------------- bf16 MFMA GEMM: C[M][N] = A[M][K] @ Bt[N][K]^T (m97 structure) ----
// 128x128 tile, BK=64, 256 thr = 4 waves (2x2), 64x64/wave = 4x4 frags of 16x16x32.
// LDS [128 rows][64 bf16 = 128B] linear for global_load_lds; XOR swizzle ((row&7)<<4)
// applied to the GLOBAL source byte and to the ds_read byte (involution, rule #21).
__global__ __launch_bounds__(256) void bt_gemm(
    const ushort_t* __restrict__ A, const ushort_t* __restrict__ Bt,
    float* __restrict__ C, int ldc)
{
  __shared__ ushort_t As[128*64];
  __shared__ ushort_t Bs[128*64];
  const int t = threadIdx.x, lane = t & 63, w = t >> 6;
  const int bm = blockIdx.y*128, bn = blockIdx.x*128;
  const int wr = w >> 1, wc = w & 1;
  const int lr = lane & 15, lg = lane >> 4;   // row-in-16, k-group

  f32x4v acc[4][4];
  #pragma unroll
  for (int fm = 0; fm < 4; ++fm)
    #pragma unroll
    for (int fn = 0; fn < 4; ++fn)
      #pragma unroll
      for (int r = 0; r < 4; ++r) acc[fm][fn][r] = 0.f;

  const char* Ab = (const char*)A;
  const char* Bb = (const char*)Bt;
  char* asb = (char*)As;
  char* bsb = (char*)Bs;

  for (int kt = 0; kt < HIDDEN*2; kt += 128) {   // byte offset within a 2048-elem row
    __syncthreads();                             // prev tile's reads done
    #pragma unroll
    for (int u = 0; u < 4; ++u) {
      const int idx = u*256 + t;                 // 16B slot id
      const int row = idx >> 3;
      const int kb  = (idx & 7) * 16;
      const int skb = kb ^ ((row & 7) << 4);     // pre-swizzled source byte
      gload16(Ab + (size_t)(bm + row)*4096 + kt + skb, asb + idx*16);
      gload16(Bb + (size_t)(bn + row)*4096 + kt + skb, bsb + idx*16);
    }
    __syncthreads();                             // vmcnt(0) drain + barrier
    #pragma unroll
    for (int kc = 0; kc < 2; ++kc) {
      bf16x8 af[4], bfr[4];
      #pragma unroll
      for (int f = 0; f < 4; ++f) {
        const int rm = wr*64 + f*16 + lr;
        af[f]  = *(const bf16x8*)(asb + rm*128 + ((kc*64 + lg*16) ^ ((rm & 7) << 4)));
        const int rn = wc*64 + f*16 + lr;
        bfr[f] = *(const bf16x8*)(bsb + rn*128 + ((kc*64 + lg*16) ^ ((rn & 7) << 4)));
      }
      #pragma unroll
      for (int fm = 0; fm < 4; ++fm)
        #pragma unroll
        for (int fn = 0; fn < 4; ++fn)
          acc[fm][fn] = __builtin_amdgcn_mfma_f32_16x16x32_bf16(af[fm], bfr[fn], acc[fm][fn], 0, 0, 0);
    }
  }

  // D layout (m89-verified): col = lane&15 (n side), row = (lane>>4)*4 + r (m side)
  #pragma unroll
  for (int fm = 0; fm < 4; ++fm) {
    const int m = bm + wr*64 + fm*16 + lg*4;
    #pragma unroll
    for (int fn = 0; fn < 4; ++fn) {
      const int n = bn + wc*64 + fn*16 + lr;
      #pragma unroll
      for (int r = 0; r < 4; ++r)
        C[(size_t)(m + r)*ldc + n] = acc[fm][fn][r];
    }
  }
}

// In-place RoPE on Q and K inside the QKV buffer (fp32).
__global__ __launch_bounds__(256) void rope_kernel(float* __restrict__ QKV)
{
  const int total = NTOK * (NH + NKV) * (HD/2);
  int idx = blockIdx.x * 256 + threadIdx.x;
  if (idx >= total) return;
  const int i   = idx & 63;
  int tmp = idx >> 6;
  const int hs  = tmp % (NH + NKV);
  const int tkn = tmp / (NH + NKV);
  const int s   = tkn & (SEQ - 1);
  const float invf = expf(-(float)i * 0.14391156831212787f);
  float sn, cs;
  sincosf((float)s * invf, &sn, &cs);
  const size_t base = (size_t)tkn * QKV_LD + (hs < NH ? hs * HD : KOFF + (hs - NH) * HD);
  const float x0 = QKV[base + i];
  const float x1 = QKV[base + i + 64];
  QKV[base + i]      = x0 * cs - x1 * sn;
  QKV[base + i + 64] = x1 * cs + x0 * sn;
}

// ---------------- MFMA flash attention (unchanged body; epilogue now writes bf16) ----
__global__ __launch_bounds__(256) void attn_mfma(
    const float* __restrict__ QKV, ushort_t* __restrict__ O)
{
  __shared__ unsigned short Kl[64*128];
  __shared__ unsigned short Vt[128*64];
  __shared__ unsigned short Pl[4][32*64];

  const int qb = blockIdx.x, bh = blockIdx.y;
  const int b = bh >> 4, h = bh & 15, hk = h >> 2;
  const int t = threadIdx.x, w = t >> 6, lane = t & 63;
  const int c = lane & 31, hi = lane >> 5;
  const int qw0 = qb*128 + w*32;
  const int qg  = qw0 + c;

  bf16x8 qf[8];
  {
    const float* qrow = QKV + (size_t)(b*SEQ + qg) * QKV_LD + h*HD;
    #pragma unroll
    for (int kc = 0; kc < 8; ++kc) {
      const float4 f0 = *(const float4*)(qrow + kc*16 + hi*8);
      const float4 f1 = *(const float4*)(qrow + kc*16 + hi*8 + 4);
      bf16x8 v;
      v[0] = (short)f2bf(f0.x*SM_SCALE); v[1] = (short)f2bf(f0.y*SM_SCALE);
      v[2] = (short)f2bf(f0.z*SM_SCALE); v[3] = (short)f2bf(f0.w*SM_SCALE);
      v[4] = (short)f2bf(f1.x*SM_SCALE); v[5] = (short)f2bf(f1.y*SM_SCALE);
      v[6] = (short)f2bf(f1.z*SM_SCALE); v[7] = (short)f2bf(f1.w*SM_SCALE);
      qf[kc] = v;
    }
  }

  f32x16 ot[4];
  #pragma unroll
  for (int nc = 0; nc < 4; ++nc)
    #pragma unroll
    for (int r = 0; r < 16; ++r) ot[nc][r] = 0.f;
  float m = -1e30f, l = 0.f;

  char* klb = (char*)Kl;
  char* vtb = (char*)Vt;
  char* plb = (char*)Pl[w];
  const int ktmax = 2*qb + 1;

  for (int kt = 0; kt <= ktmax; ++kt) {
    __syncthreads();
    {
      const int row = t >> 2, cq = t & 3;
      const float* kg = QKV + (size_t)(b*SEQ + kt*64 + row) * QKV_LD + KOFF + hk*HD + cq*32;
      const int sw = (row & 15) << 4;
      #pragma unroll
      for (int u = 0; u < 8; ++u) {
        const float4 f = ((const float4*)kg)[u];
        uint2 pv;
        pv.x = pack2(f.x, f.y); pv.y = pack2(f.z, f.w);
        *(uint2*)(klb + row*256 + ((cq*64 + u*8) ^ sw)) = pv;
      }
    }
    #pragma unroll
    for (int j = 0; j < 2; ++j) {
      const int tid = t + 256*j;
      const int kp = tid & 31, dc = tid >> 5;
      const float* vg = QKV + (size_t)(b*SEQ + kt*64 + 2*kp) * QKV_LD + VOFF + hk*HD + dc*8;
      const float4 a0 = *(const float4*)vg,            a1 = *(const float4*)(vg + 4);
      const float4 b0 = *(const float4*)(vg + QKV_LD), b1 = *(const float4*)(vg + QKV_LD + 4);
      const float x0[8] = {a0.x,a0.y,a0.z,a0.w,a1.x,a1.y,a1.z,a1.w};
      const float x1[8] = {b0.x,b0.y,b0.z,b0.w,b1.x,b1.y,b1.z,b1.w};
      #pragma unroll
      for (int jd = 0; jd < 8; ++jd) {
        const int d = dc*8 + jd;
        *(unsigned*)(vtb + d*128 + ((kp*4) ^ ((d & 7) << 4))) = pack2(x0[jd], x1[jd]);
      }
    }
    __syncthreads();

    if (kt*64 > qw0 + 31) continue;

    f32x16 s[2];
    #pragma unroll
    for (int kn = 0; kn < 2; ++kn)
      #pragma unroll
      for (int r = 0; r < 16; ++r) s[kn][r] = 0.f;
    #pragma unroll
    for (int kn = 0; kn < 2; ++kn) {
      const int row = kn*32 + c;
      const int sw = (row & 15) << 4;
      #pragma unroll
      for (int kc = 0; kc < 8; ++kc) {
        const bf16x8 ka = *(const bf16x8*)(klb + row*256 + ((kc*32 + hi*16) ^ sw));
        s[kn] = __builtin_amdgcn_mfma_f32_32x32x16_bf16(ka, qf[kc], s[kn], 0, 0, 0);
      }
    }
    // causal mask: needed iff tile extends past the wave's FIRST q-row (R3 fix)
    if (kt*64 + 63 > qw0) {
      #pragma unroll
      for (int kn = 0; kn < 2; ++kn)
        #pragma unroll
        for (int r = 0; r < 16; ++r) {
          const int kg_ = kt*64 + kn*32 + (r & 3) + 8*(r >> 2) + 4*hi;
          if (kg_ > qg) s[kn][r] = -1e30f;
        }
    }
    float mx[16];
    #pragma unroll
    for (int r = 0; r < 16; ++r) mx[r] = fmaxf(s[0][r], s[1][r]);
    #pragma unroll
    for (int st = 8; st > 0; st >>= 1)
      #pragma unroll
      for (int r = 0; r < 8; ++r)
        if (r < st) mx[r] = fmaxf(mx[r], mx[r + st]);
    float pm = fmaxf(mx[0], __shfl_xor(mx[0], 32));
    const float mnew = fmaxf(m, pm);
    const float corr = __expf(m - mnew);
    m = mnew;
    l *= corr;
    #pragma unroll
    for (int nc = 0; nc < 4; ++nc) ot[nc] *= corr;
    float ls = 0.f;
    #pragma unroll
    for (int kn = 0; kn < 2; ++kn)
      #pragma unroll
      for (int r = 0; r < 16; ++r) {
        const float p = __expf(s[kn][r] - m);
        ls += p;
        s[kn][r] = p;
      }
    l += ls;
    {
      const int swp = (c & 7) << 4;
      #pragma unroll
      for (int kn = 0; kn < 2; ++kn)
        #pragma unroll
        for (int r = 0; r < 16; r += 2) {
          const int key = kn*32 + (r & 3) + 8*(r >> 2) + 4*hi;
          *(unsigned*)(plb + c*128 + ((key*2) ^ swp)) = pack2(s[kn][r], s[kn][r+1]);
        }
    }
    asm volatile("s_waitcnt lgkmcnt(0)" ::: "memory");
    #pragma unroll
    for (int kc = 0; kc < 4; ++kc) {
      const bf16x8 pb = *(const bf16x8*)(plb + c*128 + ((kc*32 + hi*16) ^ ((c & 7) << 4)));
      #pragma unroll
      for (int nc = 0; nc < 4; ++nc) {
        const int dim = nc*32 + c;
        const bf16x8 va = *(const bf16x8*)(vtb + dim*128 + ((kc*32 + hi*16) ^ ((dim & 7) << 4)));
        ot[nc] = __builtin_amdgcn_mfma_f32_32x32x16_bf16(va, pb, ot[nc], 0, 0, 0);
      }
    }
  }

  const float lt = l + __shfl_xor(l, 32);
  const float inv = 1.f / lt;
  ushort_t* orow = O + (size_t)(b*SEQ + qg) * HIDDEN + h*HD;
  #pragma unroll
  for (int nc = 0; nc < 4; ++nc)
    #pragma unroll
    for (int r = 0; r < 16; r += 2) {
      const int dim = nc*32 + (r & 3) + 8*(r >> 2) + 4*hi;
      *(unsigned*)(orow + dim) = pack2(ot[nc][r]*inv, ot[nc][r+1]*inv);
    }
}

extern "C" void kernel_launch(void* const* d_in, const int* in_sizes, int n_in,
                              void* d_out, int out_size, void* d_ws, size_t ws_size,
                              hipStream_t stream)
{
  (void)in_sizes; (void)n_in; (void)out_size; (void)ws_size;
  const float* H  = (const float*)d_in[0];
  const float* Wq = (const float*)d_in[1];
  const float* Wk = (const float*)d_in[2];
  const float* Wv = (const float*)d_in[3];
  const float* Wo = (const float*)d_in[4];
  float* out = (float*)d_out;

  char* ws = (char*)d_ws;
  float*    QKV = (float*)ws;                          // [4096][3072] fp32 (50.3 MB)
  ushort_t* Hb  = (ushort_t*)(ws + 50331648);          // [4096][2048] bf16 (16.8 MB)
  ushort_t* Oat = Hb;                                  // aliases Hb (Hb dead after qkv_gemm)
  ushort_t* Wt  = (ushort_t*)(ws + 67108864);          // [3072][2048] bf16 (12.6 MB), reused for Wo

  conv_f2b<<<4096, 256, 0, stream>>>(H, Hb, NTOK*HIDDEN/8);
  transpose_f2b<<<dim3(64, 64), dim3(32, 8), 0, stream>>>(Wq, Wt,                         2048, 2048);
  transpose_f2b<<<dim3(16, 64), dim3(32, 8), 0, stream>>>(Wk, Wt + (size_t)2048*2048,     2048, 512);
  transpose_f2b<<<dim3(16, 64), dim3(32, 8), 0, stream>>>(Wv, Wt + (size_t)2560*2048,     2048, 512);

  bt_gemm<<<dim3(QKV_LD/128, NTOK/128), 256, 0, stream>>>(Hb, Wt, QKV, QKV_LD);

  const int rope_total = NTOK * (NH + NKV) * (HD/2);
  rope_kernel<<<(rope_total + 255)/256, 256, 0, stream>>>(QKV);

  attn_mfma<<<dim3(SEQ/128, BATCH*NH), 256, 0, stream>>>(QKV, Oat);

  transpose_f2b<<<dim3(64, 64), dim3(32, 8), 0, stream>>>(Wo, Wt, 2048, 2048);
  bt_gemm<<<dim3(HIDDEN/128, NTOK/128), 256, 0, stream>>>(Oat, Wt, out, HIDDEN);
}

// Round 5
// 251.313 us; speedup vs baseline: 10.6294x; 1.6330x over previous
//
#include <hip/hip_runtime.h>
#include <hip/hip_bf16.h>
#include <cstdint>
#include <cstddef>

#define HIDDEN   2048
#define NH       16
#define NKV      4
#define HD       128
#define SEQ      2048
#define BATCH    2
#define NTOK     (BATCH*SEQ)      // 4096
#define QKV_LD   3072             // Q(2048) | K(512) | V(512)
#define KOFF     2048
#define VOFF     2560
#define SM_SCALE 0.08838834764831845f   // 1/sqrt(128)

typedef __attribute__((ext_vector_type(8)))  short bf16x8;
typedef __attribute__((ext_vector_type(4)))  float f32x4v;
typedef __attribute__((ext_vector_type(16))) float f32x16;
typedef unsigned short ushort_t;

__device__ __forceinline__ unsigned short f2bf(float f) {
  return __builtin_bit_cast(unsigned short, __float2bfloat16(f));
}
__device__ __forceinline__ float bf2f(ushort_t u) {
  return __builtin_bit_cast(float, (unsigned)u << 16);
}
__device__ __forceinline__ unsigned pack2(float a, float b) {
  return (unsigned)f2bf(a) | ((unsigned)f2bf(b) << 16);
}

// async global->LDS, 16B/lane; LDS dest lane-linear, swizzle realized on the GLOBAL src.
__device__ __forceinline__ void gload16(const void* g, void* l) {
  __builtin_amdgcn_global_load_lds(
      (const __attribute__((address_space(1))) unsigned int*)g,
      (__attribute__((address_space(3))) unsigned int*)l, 16, 0, 0);
}

// ---------------- conversion kernels ----------------
__global__ __launch_bounds__(256) void conv_f2b(
    const float* __restrict__ in, ushort_t* __restrict__ out, int n8)
{
  const int i = blockIdx.x*256 + threadIdx.x;
  if (i >= n8) return;
  const float4 a = ((const float4*)in)[2*i];
  const float4 b = ((const float4*)in)[2*i + 1];
  uint4 r;
  r.x = pack2(a.x, a.y); r.y = pack2(a.z, a.w);
  r.z = pack2(b.x, b.y); r.w = pack2(b.z, b.w);
  ((uint4*)out)[i] = r;
}

// W[K][N] fp32 -> Wt[N][K] bf16
__global__ __launch_bounds__(256) void transpose_f2b(
    const float* __restrict__ W, ushort_t* __restrict__ Wt, int K, int N)
{
  __shared__ float tile[32][33];
  const int n0 = blockIdx.x*32, k0 = blockIdx.y*32;
  const int tx = threadIdx.x & 31, ty = threadIdx.x >> 5;
  #pragma unroll
  for (int i = 0; i < 4; ++i)
    tile[ty*4 + i][tx] = W[(size_t)(k0 + ty*4 + i)*N + n0 + tx];
  __syncthreads();
  #pragma unroll
  for (int i = 0; i < 4; ++i) {
    const int nl = ty*4 + i;
    Wt[(size_t)(n0 + nl)*K + k0 + tx] = f2bf(tile[tx][nl]);
  }
}

// ---------------- bf16 MFMA GEMM (m97 structure), templated output dtype --------
template<bool B16OUT>
__global__ __launch_bounds__(256) void bt_gemm(
    const ushort_t* __restrict__ A, const ushort_t* __restrict__ Bt,
    void* __restrict__ Cv, int ldc)
{
  __shared__ ushort_t As[128*64];
  __shared__ ushort_t Bs[128*64];
  const int t = threadIdx.x, lane = t & 63, w = t >> 6;
  const int bm = blockIdx.y*128, bn = blockIdx.x*128;
  const int wr = w >> 1, wc = w & 1;
  const int lr = lane & 15, lg = lane >> 4;

  f32x4v acc[4][4];
  #pragma unroll
  for (int fm = 0; fm < 4; ++fm)
    #pragma unroll
    for (int fn = 0; fn < 4; ++fn)
      #pragma unroll
      for (int r = 0; r < 4; ++r) acc[fm][fn][r] = 0.f;

  const char* Ab = (const char*)A;
  const char* Bb = (const char*)Bt;
  char* asb = (char*)As;
  char* bsb = (char*)Bs;

  for (int kt = 0; kt < HIDDEN*2; kt += 128) {
    __syncthreads();
    #pragma unroll
    for (int u = 0; u < 4; ++u) {
      const int idx = u*256 + t;
      const int row = idx >> 3;
      const int kb  = (idx & 7) * 16;
      const int skb = kb ^ ((row & 7) << 4);
      gload16(Ab + (size_t)(bm + row)*4096 + kt + skb, asb + idx*16);
      gload16(Bb + (size_t)(bn + row)*4096 + kt + skb, bsb + idx*16);
    }
    __syncthreads();
    #pragma unroll
    for (int kc = 0; kc < 2; ++kc) {
      bf16x8 af[4], bfr[4];
      #pragma unroll
      for (int f = 0; f < 4; ++f) {
        const int rm = wr*64 + f*16 + lr;
        af[f]  = *(const bf16x8*)(asb + rm*128 + ((kc*64 + lg*16) ^ ((rm & 7) << 4)));
        const int rn = wc*64 + f*16 + lr;
        bfr[f] = *(const bf16x8*)(bsb + rn*128 + ((kc*64 + lg*16) ^ ((rn & 7) << 4)));
      }
      #pragma unroll
      for (int fm = 0; fm < 4; ++fm)
        #pragma unroll
        for (int fn = 0; fn < 4; ++fn)
          acc[fm][fn] = __builtin_amdgcn_mfma_f32_16x16x32_bf16(af[fm], bfr[fn], acc[fm][fn], 0, 0, 0);
    }
  }

  #pragma unroll
  for (int fm = 0; fm < 4; ++fm) {
    const int m = bm + wr*64 + fm*16 + lg*4;
    #pragma unroll
    for (int fn = 0; fn < 4; ++fn) {
      const int n = bn + wc*64 + fn*16 + lr;
      #pragma unroll
      for (int r = 0; r < 4; ++r) {
        if constexpr (B16OUT)
          ((ushort_t*)Cv)[(size_t)(m + r)*ldc + n] = f2bf(acc[fm][fn][r]);
        else
          ((float*)Cv)[(size_t)(m + r)*ldc + n] = acc[fm][fn][r];
      }
    }
  }
}

// RoPE on bf16 QKV; writes Qo (SM_SCALE folded) and Ko[b,hk][s][d].
__global__ __launch_bounds__(256) void rope_conv(
    const ushort_t* __restrict__ QKVb, ushort_t* __restrict__ Qo,
    ushort_t* __restrict__ Ko)
{
  const int total = NTOK * (NH + NKV) * (HD/2);
  int idx = blockIdx.x * 256 + threadIdx.x;
  if (idx >= total) return;
  const int i   = idx & 63;
  int tmp = idx >> 6;
  const int hs  = tmp % (NH + NKV);
  const int tkn = tmp / (NH + NKV);
  const int s   = tkn & (SEQ - 1);
  const int b   = tkn >> 11;
  const float invf = expf(-(float)i * 0.14391156831212787f);
  float sn, cs;
  sincosf((float)s * invf, &sn, &cs);
  const size_t base = (size_t)tkn * QKV_LD + (hs < NH ? hs * HD : KOFF + (hs - NH) * HD);
  const float x0 = bf2f(QKVb[base + i]);
  const float x1 = bf2f(QKVb[base + i + 64]);
  const float y0 = x0 * cs - x1 * sn;
  const float y1 = x1 * cs + x0 * sn;
  if (hs < NH) {
    ushort_t* q = Qo + (size_t)tkn * HIDDEN + hs * HD;
    q[i]      = f2bf(y0 * SM_SCALE);
    q[i + 64] = f2bf(y1 * SM_SCALE);
  } else {
    ushort_t* k = Ko + ((size_t)(b*NKV + (hs - NH))*SEQ + s) * HD;
    k[i]      = f2bf(y0);
    k[i + 64] = f2bf(y1);
  }
}

// V columns of QKVb -> Vtb[b,hk][d][s] (bf16 transpose via LDS tile)
__global__ __launch_bounds__(256) void vt_conv(
    const ushort_t* __restrict__ QKVb, ushort_t* __restrict__ Vtb)
{
  __shared__ ushort_t tile[32][33];
  const int s0 = blockIdx.x*32;
  const int d0 = (blockIdx.y & 3)*32;
  const int bk = blockIdx.y >> 2;           // b*NKV+hk
  const int b = bk >> 2, hk = bk & 3;
  const int tx = threadIdx.x & 31, ty = threadIdx.x >> 5;
  #pragma unroll
  for (int i = 0; i < 4; ++i) {
    const int sl = ty*4 + i;
    tile[sl][tx] = QKVb[(size_t)(b*SEQ + s0 + sl)*QKV_LD + VOFF + hk*HD + d0 + tx];
  }
  __syncthreads();
  #pragma unroll
  for (int i = 0; i < 4; ++i) {
    const int dl = ty*4 + i;
    Vtb[((size_t)bk*HD + d0 + dl)*SEQ + s0 + tx] = tile[tx][dl];
  }
}

// ---------------- MFMA flash attention v2 ----------------
// 256 uniform blocks: block bx handles q-tiles {bx, 15-bx} (34 K-tile stagings each).
// K/V staged bf16 via global_load_lds (pre-swizzled source), double-buffered 2-phase.
__global__ __launch_bounds__(256) void attn_mfma2(
    const ushort_t* __restrict__ Qb, const ushort_t* __restrict__ Kb,
    const ushort_t* __restrict__ Vtb, ushort_t* __restrict__ O)
{
  __shared__ ushort_t Kl[2][64*128];
  __shared__ ushort_t Vl[2][128*64];
  __shared__ ushort_t Pl[4][32*64];

  const int bx = blockIdx.x, bh = blockIdx.y;
  const int b = bh >> 4, h = bh & 15, hk = h >> 2;
  const int t = threadIdx.x, w = t >> 6, lane = t & 63;
  const int c = lane & 31, hi = lane >> 5;

  const char* Kbb = (const char*)(Kb + (size_t)(b*NKV + hk)*SEQ*HD);
  const char* Vbb = (const char*)(Vtb + (size_t)(b*NKV + hk)*HD*SEQ);
  char* plb = (char*)Pl[w];

  // per-thread staging offsets (constant across tiles)
  int ksrc[4], vsrc[4], ldst[4];
  #pragma unroll
  for (int u = 0; u < 4; ++u) {
    const int idx = u*256 + t;
    const int krow = idx >> 4, kof = (idx & 15) << 4;   // K tile: 64 rows x 256B
    ksrc[u] = krow*256 + (kof ^ ((krow & 15) << 4));
    const int vd = idx >> 3,  vof = (idx & 7) << 4;     // V tile: 128 rows x 128B
    vsrc[u] = vd*(SEQ*2) + (vof ^ ((vd & 7) << 4));
    ldst[u] = idx*16;
  }

  #pragma unroll 1
  for (int pi = 0; pi < 2; ++pi) {
    const int qb  = pi ? (15 - bx) : bx;
    const int qw0 = qb*128 + w*32;
    const int qg  = qw0 + c;

    bf16x8 qf[8];
    {
      const ushort_t* qrow = Qb + (size_t)(b*SEQ + qg)*HIDDEN + h*HD;
      #pragma unroll
      for (int kc = 0; kc < 8; ++kc)
        qf[kc] = *(const bf16x8*)(qrow + kc*16 + hi*8);
    }

    f32x16 ot[4];
    #pragma unroll
    for (int nc = 0; nc < 4; ++nc)
      #pragma unroll
      for (int r = 0; r < 16; ++r) ot[nc][r] = 0.f;
    float m = -1e30f, l = 0.f;
    const int ktmax = 2*qb + 1;

    // prologue: stage tile 0 into buf 0
    #pragma unroll
    for (int u = 0; u < 4; ++u) {
      gload16(Kbb + ksrc[u], (char*)Kl[0] + ldst[u]);
      gload16(Vbb + vsrc[u], (char*)Vl[0] + ldst[u]);
    }
    __syncthreads();

    int cur = 0;
    for (int kt = 0; kt <= ktmax; ++kt) {
      if (kt < ktmax) {      // issue next-tile loads before computing current
        const int nb = cur ^ 1;
        const size_t kto = (size_t)(kt + 1) * 16384;   // 64 rows * 256B
        const int    vto = (kt + 1) * 128;             // 64 keys * 2B within V rows
        #pragma unroll
        for (int u = 0; u < 4; ++u) {
          gload16(Kbb + kto + ksrc[u], (char*)Kl[nb] + ldst[u]);
          gload16(Vbb + vto + vsrc[u], (char*)Vl[nb] + ldst[u]);
        }
      }
      if (kt*64 <= qw0 + 31) {
        const char* klb = (const char*)Kl[cur];
        const char* vlb = (const char*)Vl[cur];
        // ---- QK^T (swapped): D col = q-row, rows = keys
        f32x16 s[2];
        #pragma unroll
        for (int kn = 0; kn < 2; ++kn)
          #pragma unroll
          for (int r = 0; r < 16; ++r) s[kn][r] = 0.f;
        #pragma unroll
        for (int kn = 0; kn < 2; ++kn) {
          const int row = kn*32 + c;
          const int sw = (row & 15) << 4;
          #pragma unroll
          for (int kc = 0; kc < 8; ++kc) {
            const bf16x8 ka = *(const bf16x8*)(klb + row*256 + ((kc*32 + hi*16) ^ sw));
            s[kn] = __builtin_amdgcn_mfma_f32_32x32x16_bf16(ka, qf[kc], s[kn], 0, 0, 0);
          }
        }
        // ---- causal mask (iff tile extends past wave's FIRST q-row)
        if (kt*64 + 63 > qw0) {
          #pragma unroll
          for (int kn = 0; kn < 2; ++kn)
            #pragma unroll
            for (int r = 0; r < 16; ++r) {
              const int kg_ = kt*64 + kn*32 + (r & 3) + 8*(r >> 2) + 4*hi;
              if (kg_ > qg) s[kn][r] = -1e30f;
            }
        }
        // ---- online softmax (lane-local per q-row)
        float mx[16];
        #pragma unroll
        for (int r = 0; r < 16; ++r) mx[r] = fmaxf(s[0][r], s[1][r]);
        #pragma unroll
        for (int st = 8; st > 0; st >>= 1)
          #pragma unroll
          for (int r = 0; r < 8; ++r)
            if (r < st) mx[r] = fmaxf(mx[r], mx[r + st]);
        const float pm = fmaxf(mx[0], __shfl_xor(mx[0], 32));
        const float mnew = fmaxf(m, pm);
        const float corr = __expf(m - mnew);
        m = mnew;
        l *= corr;
        #pragma unroll
        for (int nc = 0; nc < 4; ++nc) ot[nc] *= corr;
        float ls = 0.f;
        #pragma unroll
        for (int kn = 0; kn < 2; ++kn)
          #pragma unroll
          for (int r = 0; r < 16; ++r) {
            const float p = __expf(s[kn][r] - m);
            ls += p;
            s[kn][r] = p;
          }
        l += ls;
        // ---- P^T -> Pl[qrow][key]
        {
          const int swp = (c & 7) << 4;
          #pragma unroll
          for (int kn = 0; kn < 2; ++kn)
            #pragma unroll
            for (int r = 0; r < 16; r += 2) {
              const int key = kn*32 + (r & 3) + 8*(r >> 2) + 4*hi;
              *(unsigned*)(plb + c*128 + ((key*2) ^ swp)) = pack2(s[kn][r], s[kn][r+1]);
            }
        }
        asm volatile("s_waitcnt lgkmcnt(0)" ::: "memory");
        // ---- PV: O^T += V^T . P^T
        #pragma unroll
        for (int kc = 0; kc < 4; ++kc) {
          const bf16x8 pb = *(const bf16x8*)(plb + c*128 + ((kc*32 + hi*16) ^ ((c & 7) << 4)));
          #pragma unroll
          for (int nc = 0; nc < 4; ++nc) {
            const int dim = nc*32 + c;
            const bf16x8 va = *(const bf16x8*)(vlb + dim*128 + ((kc*32 + hi*16) ^ ((dim & 7) << 4)));
            ot[nc] = __builtin_amdgcn_mfma_f32_32x32x16_bf16(va, pb, ot[nc], 0, 0, 0);
          }
        }
      }
      __syncthreads();
      cur ^= 1;
    }

    // ---- epilogue
    const float lt = l + __shfl_xor(l, 32);
    const float inv = 1.f / lt;
    ushort_t* orow = O + (size_t)(b*SEQ + qg) * HIDDEN + h*HD;
    #pragma unroll
    for (int nc = 0; nc < 4; ++nc)
      #pragma unroll
      for (int r = 0; r < 16; r += 2) {
        const int dim = nc*32 + (r & 3) + 8*(r >> 2) + 4*hi;
        *(unsigned*)(orow + dim) = pack2(ot[nc][r]*inv, ot[nc][r+1]*inv);
      }
  }
}

extern "C" void kernel_launch(void* const* d_in, const int* in_sizes, int n_in,
                              void* d_out, int out_size, void* d_ws, size_t ws_size,
                              hipStream_t stream)
{
  (void)in_sizes; (void)n_in; (void)out_size; (void)ws_size;
  const float* H  = (const float*)d_in[0];
  const float* Wq = (const float*)d_in[1];
  const float* Wk = (const float*)d_in[2];
  const float* Wv = (const float*)d_in[3];
  const float* Wo = (const float*)d_in[4];
  float* out = (float*)d_out;

  char* ws = (char*)d_ws;
  ushort_t* QKVb = (ushort_t*)ws;                      // [4096][3072] bf16  25.2 MB
  ushort_t* Hb   = (ushort_t*)(ws + 25165824);         // [4096][2048] bf16  16.8 MB (dead after gemm -> Qb)
  ushort_t* Qb   = Hb;
  ushort_t* Wt   = (ushort_t*)(ws + 41943040);         // [3072][2048] bf16  12.6 MB (reused for Wo)
  ushort_t* Kb   = (ushort_t*)(ws + 54525952);         // [2*4][2048][128]    4.2 MB
  ushort_t* Vtb  = (ushort_t*)(ws + 58720256);         // [2*4][128][2048]    4.2 MB
  ushort_t* Oat  = (ushort_t*)(ws + 62914560);         // [4096][2048] bf16  16.8 MB
                                                       // end 79.7 MB

  conv_f2b<<<4096, 256, 0, stream>>>(H, Hb, NTOK*HIDDEN/8);
  transpose_f2b<<<dim3(64, 64), 256, 0, stream>>>(Wq, Wt,                     2048, 2048);
  transpose_f2b<<<dim3(16, 64), 256, 0, stream>>>(Wk, Wt + (size_t)2048*2048, 2048, 512);
  transpose_f2b<<<dim3(16, 64), 256, 0, stream>>>(Wv, Wt + (size_t)2560*2048, 2048, 512);

  bt_gemm<true><<<dim3(QKV_LD/128, NTOK/128), 256, 0, stream>>>(Hb, Wt, QKVb, QKV_LD);

  const int rope_total = NTOK * (NH + NKV) * (HD/2);
  rope_conv<<<(rope_total + 255)/256, 256, 0, stream>>>(QKVb, Qb, Kb);
  vt_conv<<<dim3(SEQ/32, 32), 256, 0, stream>>>(QKVb, Vtb);

  attn_mfma2<<<dim3(8, BATCH*NH), 256, 0, stream>>>(Qb, Kb, Vtb, Oat);

  transpose_f2b<<<dim3(64, 64), 256, 0, stream>>>(Wo, Wt, 2048, 2048);
  bt_gemm<false><<<dim3(HIDDEN/128, NTOK/128), 256, 0, stream>>>(Oat, Wt, out, HIDDEN);
}